// Round 2
// baseline (76.905 us; speedup 1.0000x reference)
//
#include <hip/hip_runtime.h>

// Plenoxel query: per-point voxel gather + SH-basis color.
// R2: 4 points/thread -> all streaming I/O as aligned float4; nontemporal
// hints on touch-once streams to preserve L2/L3 residency of the voxel grid.

typedef float f4 __attribute__((ext_vector_type(4)));

__device__ __forceinline__ void eval_point(
    float x0, float x1, float x2,
    float dx, float dy, float dz,
    const float* __restrict__ vg,
    float& c0, float& c1, float& c2, float& sg)
{
    const float C0   = 0.28209479177387814f;
    const float C1   = 0.4886025119029199f;
    const float C2_0 = 1.0925484305920792f;
    const float C2_1 = -1.0925484305920792f;
    const float C2_2 = 0.31539156525252005f;
    const float C2_3 = -1.0925484305920792f;
    const float C2_4 = 0.5462742152960396f;

    c0 = 0.f; c1 = 0.f; c2 = 0.f; sg = 0.f;
    const bool mask = (fabsf(x0) < 1.0f) & (fabsf(x1) < 1.0f) & (fabsf(x2) < 1.0f);
    if (mask) {
        // idx = clip((x*64 + 64).astype(int32), 0, 127); C cast truncates
        // toward zero, matching JAX astype(int32).
        int ix = (int)(x0 * 64.f + 64.f);
        int iy = (int)(x1 * 64.f + 64.f);
        int iz = (int)(x2 * 64.f + 64.f);
        ix = min(max(ix, 0), 127);
        iy = min(max(iy, 0), 127);
        iz = min(max(iz, 0), 127);

        // 28-float record, 112 B = 7x16 B -> float4 loads are aligned.
        const f4* rec = (const f4*)(vg + (size_t)(((ix * 128 + iy) * 128 + iz)) * 28);
        const f4 r0 = rec[0];
        const f4 r1 = rec[1];
        const f4 r2 = rec[2];
        const f4 r3 = rec[3];
        const f4 r4 = rec[4];
        const f4 r5 = rec[5];
        const f4 r6 = rec[6];

        const float sh0 = C0;
        const float sh1 = -C1 * dy;
        const float sh2 = C1 * dz;
        const float sh3 = -C1 * dx;
        const float sh4 = C2_0 * dx * dy;
        const float sh5 = C2_1 * dy * dz;
        const float sh6 = C2_2 * (2.f * dz * dz - dx * dx - dy * dy);
        const float sh7 = C2_3 * dx * dz;
        const float sh8 = C2_4 * (dx * dx - dy * dy);

        sg = fmaxf(r0.x, 0.f);  // relu(tmp[0])

        // k[c][j] = tmp[1 + 9c + j]
        c0 = r0.y * sh0 + r0.z * sh1 + r0.w * sh2 + r1.x * sh3 + r1.y * sh4 +
             r1.z * sh5 + r1.w * sh6 + r2.x * sh7 + r2.y * sh8;
        c1 = r2.z * sh0 + r2.w * sh1 + r3.x * sh2 + r3.y * sh3 + r3.z * sh4 +
             r3.w * sh5 + r4.x * sh6 + r4.y * sh7 + r4.z * sh8;
        c2 = r4.w * sh0 + r5.x * sh1 + r5.y * sh2 + r5.z * sh3 + r5.w * sh4 +
             r6.x * sh5 + r6.y * sh6 + r6.z * sh7 + r6.w * sh8;
    }
}

__global__ __launch_bounds__(256) void plenoxel_kernel(
    const f4* __restrict__ x4,
    const f4* __restrict__ d4,
    const float* __restrict__ vg,
    f4* __restrict__ outc,   // color region, float4 view (3 f4 per 4 points)
    f4* __restrict__ outs,   // sigma region, float4 view (1 f4 per 4 points)
    int nQuad)               // P/4
{
    const int stride = gridDim.x * blockDim.x;
    for (int q = blockIdx.x * blockDim.x + threadIdx.x; q < nQuad; q += stride) {
        // 4 points' positions: 12 floats = 3 aligned float4, nontemporal.
        const f4 xa = __builtin_nontemporal_load(&x4[3 * q + 0]);
        const f4 xb = __builtin_nontemporal_load(&x4[3 * q + 1]);
        const f4 xc = __builtin_nontemporal_load(&x4[3 * q + 2]);

        const bool m0 = (fabsf(xa.x) < 1.f) & (fabsf(xa.y) < 1.f) & (fabsf(xa.z) < 1.f);
        const bool m1 = (fabsf(xa.w) < 1.f) & (fabsf(xb.x) < 1.f) & (fabsf(xb.y) < 1.f);
        const bool m2 = (fabsf(xb.z) < 1.f) & (fabsf(xb.w) < 1.f) & (fabsf(xc.x) < 1.f);
        const bool m3 = (fabsf(xc.y) < 1.f) & (fabsf(xc.z) < 1.f) & (fabsf(xc.w) < 1.f);

        f4 da = {0.f, 0.f, 0.f, 0.f}, db = da, dc = da;
        if (m0 | m1 | m2 | m3) {
            da = __builtin_nontemporal_load(&d4[3 * q + 0]);
            db = __builtin_nontemporal_load(&d4[3 * q + 1]);
            dc = __builtin_nontemporal_load(&d4[3 * q + 2]);
        }

        float c00, c01, c02, s0;
        float c10, c11, c12, s1;
        float c20, c21, c22, s2;
        float c30, c31, c32, s3;
        eval_point(xa.x, xa.y, xa.z, da.x, da.y, da.z, vg, c00, c01, c02, s0);
        eval_point(xa.w, xb.x, xb.y, da.w, db.x, db.y, vg, c10, c11, c12, s1);
        eval_point(xb.z, xb.w, xc.x, db.z, db.w, dc.x, vg, c20, c21, c22, s2);
        eval_point(xc.y, xc.z, xc.w, dc.y, dc.z, dc.w, vg, c30, c31, c32, s3);

        // color: 12 contiguous floats -> 3 float4 nontemporal stores
        f4 o0 = {c00, c01, c02, c10};
        f4 o1 = {c11, c12, c20, c21};
        f4 o2 = {c22, c30, c31, c32};
        __builtin_nontemporal_store(o0, &outc[3 * q + 0]);
        __builtin_nontemporal_store(o1, &outc[3 * q + 1]);
        __builtin_nontemporal_store(o2, &outc[3 * q + 2]);

        f4 os = {s0, s1, s2, s3};
        __builtin_nontemporal_store(os, &outs[q]);
    }
}

extern "C" void kernel_launch(void* const* d_in, const int* in_sizes, int n_in,
                              void* d_out, int out_size, void* d_ws, size_t ws_size,
                              hipStream_t stream) {
    const f4* x4 = (const f4*)d_in[0];
    const f4* d4 = (const f4*)d_in[1];
    const float* vg = (const float*)d_in[2];
    float* out = (float*)d_out;
    const int P = in_sizes[0] / 3;
    const int nQuad = P / 4;  // P = 4194304, divisible by 4

    f4* outc = (f4*)out;                       // 3P floats of color
    f4* outs = (f4*)(out + (size_t)3 * P);     // P floats of sigma (16B-aligned)

    const int block = 256;
    const int grid = 2048;  // 8 blocks/CU; grid-stride x2 over nQuad=1M
    plenoxel_kernel<<<grid, block, 0, stream>>>(x4, d4, vg, outc, outs, nQuad);
}

// Round 4
// 75.310 us; speedup vs baseline: 1.0212x; 1.0212x over previous
//
#include <hip/hip_runtime.h>

// Plenoxel query, R4: wave-level mask compaction (R3 + overflow fix).
// Each wave processes CHUNK=192 consecutive points: ballot+mbcnt-compact the
// ~32% masked points into wave-private LDS, gather voxel records with ~95%
// dense lanes, stage results in LDS, write out coalesced float4.
// R3 bug: staging-zero loop wrote 192 f4 into a 144-f4 wave-private region,
// corrupting the neighboring wave's staging. Now clamped to 144.

typedef float f4 __attribute__((ext_vector_type(4)));

#define CHUNK 192
#define WPB 4  // waves per 256-thread block

__global__ __launch_bounds__(256) void plenoxel_kernel(
    const float* __restrict__ x,
    const float* __restrict__ d,
    const float* __restrict__ vg,
    float* __restrict__ out,   // [3P] color floats, then [P] sigma floats
    int P, int nChunks)
{
    __shared__ unsigned int s_pack[WPB][CHUNK];
    __shared__ f4 s_resc[WPB][(3 * CHUNK) / 4];  // 144 f4 = 576 floats
    __shared__ f4 s_ress[WPB][CHUNK / 4];        // 48 f4 = 192 floats

    const float C0   = 0.28209479177387814f;
    const float C1   = 0.4886025119029199f;
    const float C2_0 = 1.0925484305920792f;
    const float C2_1 = -1.0925484305920792f;
    const float C2_2 = 0.31539156525252005f;
    const float C2_3 = -1.0925484305920792f;
    const float C2_4 = 0.5462742152960396f;

    const int lane = threadIdx.x & 63;
    const int wid  = threadIdx.x >> 6;
    const int gw   = blockIdx.x * WPB + wid;
    const int nw   = gridDim.x * WPB;

    unsigned int* pack = s_pack[wid];
    float* resc = (float*)s_resc[wid];
    float* ress = (float*)s_ress[wid];

    const f4 z4 = {0.f, 0.f, 0.f, 0.f};

    for (int chunk = gw; chunk < nChunks; chunk += nw) {
        const int base = chunk * CHUNK;
        const int valid = min(CHUNK, P - base);  // P%64==0 -> valid%64==0

        // zero result staging: exactly 144 f4 color + 48 f4 sigma (wave-private)
        s_resc[wid][lane] = z4;
        s_resc[wid][64 + lane] = z4;
        if (lane < 16) s_resc[wid][128 + lane] = z4;
        if (lane < CHUNK / 4) s_ress[wid][lane] = z4;

        // --- compaction: 3 rounds of 64 points ---
        int cnt = 0;
        #pragma unroll
        for (int r = 0; r < 3; ++r) {
            const int slot = r * 64 + lane;
            const int p = base + slot;
            bool m = false;
            unsigned int vox = 0;
            if (slot < valid) {
                const float x0 = __builtin_nontemporal_load(&x[3 * p + 0]);
                const float x1 = __builtin_nontemporal_load(&x[3 * p + 1]);
                const float x2 = __builtin_nontemporal_load(&x[3 * p + 2]);
                m = (fabsf(x0) < 1.f) & (fabsf(x1) < 1.f) & (fabsf(x2) < 1.f);
                if (m) {
                    // astype(int32) truncates toward zero; then clip to [0,127]
                    int ix = min(max((int)(x0 * 64.f + 64.f), 0), 127);
                    int iy = min(max((int)(x1 * 64.f + 64.f), 0), 127);
                    int iz = min(max((int)(x2 * 64.f + 64.f), 0), 127);
                    vox = (unsigned int)((ix * 128 + iy) * 128 + iz);  // < 2^21
                }
            }
            const unsigned long long bal = __ballot(m);
            const int pos = __builtin_amdgcn_mbcnt_hi(
                (unsigned int)(bal >> 32),
                __builtin_amdgcn_mbcnt_lo((unsigned int)bal, 0));
            if (m) pack[cnt + pos] = vox | ((unsigned int)slot << 21);
            cnt += (int)__popcll(bal);
        }

        // --- dense gather + SH compute ---
        for (int t = lane; t < cnt; t += 64) {
            const unsigned int pk = pack[t];
            const unsigned int vox = pk & 0x1FFFFFu;
            const int slot = (int)(pk >> 21);
            const int p2 = base + slot;

            const f4* rec = (const f4*)(vg + (size_t)vox * 28);
            const f4 r0 = rec[0];
            const f4 r1 = rec[1];
            const f4 r2 = rec[2];
            const f4 r3 = rec[3];
            const f4 r4 = rec[4];
            const f4 r5 = rec[5];
            const f4 r6 = rec[6];

            const float dx = __builtin_nontemporal_load(&d[3 * p2 + 0]);
            const float dy = __builtin_nontemporal_load(&d[3 * p2 + 1]);
            const float dz = __builtin_nontemporal_load(&d[3 * p2 + 2]);

            const float sh0 = C0;
            const float sh1 = -C1 * dy;
            const float sh2 = C1 * dz;
            const float sh3 = -C1 * dx;
            const float sh4 = C2_0 * dx * dy;
            const float sh5 = C2_1 * dy * dz;
            const float sh6 = C2_2 * (2.f * dz * dz - dx * dx - dy * dy);
            const float sh7 = C2_3 * dx * dz;
            const float sh8 = C2_4 * (dx * dx - dy * dy);

            const float sg = fmaxf(r0.x, 0.f);
            const float c0 = r0.y * sh0 + r0.z * sh1 + r0.w * sh2 + r1.x * sh3 +
                             r1.y * sh4 + r1.z * sh5 + r1.w * sh6 + r2.x * sh7 +
                             r2.y * sh8;
            const float c1 = r2.z * sh0 + r2.w * sh1 + r3.x * sh2 + r3.y * sh3 +
                             r3.z * sh4 + r3.w * sh5 + r4.x * sh6 + r4.y * sh7 +
                             r4.z * sh8;
            const float c2 = r4.w * sh0 + r5.x * sh1 + r5.y * sh2 + r5.z * sh3 +
                             r5.w * sh4 + r6.x * sh5 + r6.y * sh6 + r6.z * sh7 +
                             r6.w * sh8;

            resc[slot * 3 + 0] = c0;   // stride-3 scatter: coprime with 32 banks
            resc[slot * 3 + 1] = c1;
            resc[slot * 3 + 2] = c2;
            ress[slot] = sg;
        }

        // --- coalesced write-out from LDS ---
        f4* gc = (f4*)(out + (size_t)3 * base);        // 2304*chunk bytes: aligned
        const int nc4 = (3 * valid) >> 2;              // 144 (or 48 on tail)
        for (int t = lane; t < nc4; t += 64)
            __builtin_nontemporal_store(s_resc[wid][t], &gc[t]);

        f4* gs = (f4*)(out + (size_t)3 * P + base);    // aligned
        const int ns4 = valid >> 2;
        for (int t = lane; t < ns4; t += 64)
            __builtin_nontemporal_store(s_ress[wid][t], &gs[t]);
    }
}

extern "C" void kernel_launch(void* const* d_in, const int* in_sizes, int n_in,
                              void* d_out, int out_size, void* d_ws, size_t ws_size,
                              hipStream_t stream) {
    const float* x  = (const float*)d_in[0];
    const float* d  = (const float*)d_in[1];
    const float* vg = (const float*)d_in[2];
    float* out = (float*)d_out;
    const int P = in_sizes[0] / 3;
    const int nChunks = (P + CHUNK - 1) / CHUNK;

    const int block = 256;  // 4 waves
    const int grid = 2048;  // 8192 waves, ~2.7 chunks each
    plenoxel_kernel<<<grid, block, 0, stream>>>(x, d, vg, out, P, nChunks);
}

// Round 5
// 73.580 us; speedup vs baseline: 1.0452x; 1.0235x over previous
//
#include <hip/hip_runtime.h>

// Plenoxel query, R5: R1 structure (simplest of the three equal-fastest
// variants) + __launch_bounds__(256, 8) to force VGPR<=64 -> guaranteed
// 8 waves/SIMD (32 waves/CU) for maximal outstanding random gather requests
// (DRAM bank-level parallelism). Final occupancy knob before roofline call.

typedef float f4 __attribute__((ext_vector_type(4)));

__global__ __launch_bounds__(256, 8) void plenoxel_kernel(
    const float* __restrict__ x,
    const float* __restrict__ d,
    const float* __restrict__ vg,
    float* __restrict__ out,
    int P)
{
    const float C0   = 0.28209479177387814f;
    const float C1   = 0.4886025119029199f;
    const float C2_0 = 1.0925484305920792f;
    const float C2_1 = -1.0925484305920792f;
    const float C2_2 = 0.31539156525252005f;
    const float C2_3 = -1.0925484305920792f;
    const float C2_4 = 0.5462742152960396f;

    const int stride = gridDim.x * blockDim.x;
    for (int p = blockIdx.x * blockDim.x + threadIdx.x; p < P; p += stride) {
        const float x0 = x[3 * p + 0];
        const float x1 = x[3 * p + 1];
        const float x2 = x[3 * p + 2];
        const bool mask = (fabsf(x0) < 1.0f) & (fabsf(x1) < 1.0f) & (fabsf(x2) < 1.0f);

        float c0 = 0.f, c1 = 0.f, c2 = 0.f, sg = 0.f;
        if (mask) {
            // astype(int32) truncates toward zero, then clip to [0,127]
            int ix = min(max((int)(x0 * 64.f + 64.f), 0), 127);
            int iy = min(max((int)(x1 * 64.f + 64.f), 0), 127);
            int iz = min(max((int)(x2 * 64.f + 64.f), 0), 127);

            const f4* rec =
                (const f4*)(vg + (size_t)(((ix * 128 + iy) * 128 + iz)) * 28);
            const f4 r0 = rec[0];
            const f4 r1 = rec[1];
            const f4 r2 = rec[2];
            const f4 r3 = rec[3];
            const f4 r4 = rec[4];
            const f4 r5 = rec[5];
            const f4 r6 = rec[6];

            const float dx = d[3 * p + 0];
            const float dy = d[3 * p + 1];
            const float dz = d[3 * p + 2];

            const float sh1 = -C1 * dy;
            const float sh2 = C1 * dz;
            const float sh3 = -C1 * dx;
            const float sh4 = C2_0 * dx * dy;
            const float sh5 = C2_1 * dy * dz;
            const float sh6 = C2_2 * (2.f * dz * dz - dx * dx - dy * dy);
            const float sh7 = C2_3 * dx * dz;
            const float sh8 = C2_4 * (dx * dx - dy * dy);

            sg = fmaxf(r0.x, 0.f);  // relu(tmp[0])

            // k[c][j] = tmp[1 + 9c + j]
            c0 = r0.y * C0 + r0.z * sh1 + r0.w * sh2 + r1.x * sh3 + r1.y * sh4 +
                 r1.z * sh5 + r1.w * sh6 + r2.x * sh7 + r2.y * sh8;
            c1 = r2.z * C0 + r2.w * sh1 + r3.x * sh2 + r3.y * sh3 + r3.z * sh4 +
                 r3.w * sh5 + r4.x * sh6 + r4.y * sh7 + r4.z * sh8;
            c2 = r4.w * C0 + r5.x * sh1 + r5.y * sh2 + r5.z * sh3 + r5.w * sh4 +
                 r6.x * sh5 + r6.y * sh6 + r6.z * sh7 + r6.w * sh8;
        }

        __builtin_nontemporal_store(c0, &out[3 * p + 0]);
        __builtin_nontemporal_store(c1, &out[3 * p + 1]);
        __builtin_nontemporal_store(c2, &out[3 * p + 2]);
        __builtin_nontemporal_store(sg, &out[(size_t)3 * P + p]);
    }
}

extern "C" void kernel_launch(void* const* d_in, const int* in_sizes, int n_in,
                              void* d_out, int out_size, void* d_ws, size_t ws_size,
                              hipStream_t stream) {
    const float* x  = (const float*)d_in[0];
    const float* d  = (const float*)d_in[1];
    const float* vg = (const float*)d_in[2];
    float* out = (float*)d_out;
    const int P = in_sizes[0] / 3;

    const int block = 256;
    const int grid = 2048;  // 8192 waves = 32/CU with forced 8 waves/EU
    plenoxel_kernel<<<grid, block, 0, stream>>>(x, d, vg, out, P);
}